// Round 4
// baseline (292.251 us; speedup 1.0000x reference)
//
#include <hip/hip_runtime.h>
#include <hip/hip_fp16.h>

#define HW (512 * 1024)          // 524288 = 2^19
#define NPIX (4 * HW)            // 2097152
#define NCLS 19
#define NB 256                   // lovasz histogram buckets over [0,8)
#define BSCALE 32.0f             // bucket width 1/32
#define L2E 1.4426950408889634f
#define LN2 0.6931471805599453f

#define NTHR 256
#define NBLK 1024
#define ITERS 4                  // float2 per iter -> 8 px/thread -> 2048 px/block

// acc layout (doubles): 0 ce, 1 focal, 2..20 inter[19], 21..39 sumP[19],
//                       40..58 cnt[19]
#define ACC_BYTES 512
#define HIST_ENTRIES (NCLS * NB)
#define NREP 2                   // global hist replicas (atomic contention)

// ---------------- K1: single pass over logits ----------------
__global__ __launch_bounds__(NTHR, 4) void k_main(const float* __restrict__ lg,
                                                  const int* __restrict__ masks,
                                                  unsigned* __restrict__ gHist,
                                                  double* __restrict__ acc) {
    __shared__ unsigned hist[HIST_ENTRIES];     // packed: low16 total, high16 bg
    __shared__ float sInter[NCLS];
    __shared__ unsigned sCnt[NCLS];
    __shared__ float sSumP[NCLS];
    __shared__ float sCE, sFocal;
    int tid = threadIdx.x;
    for (int k = tid; k < HIST_ENTRIES; k += NTHR) hist[k] = 0u;
    if (tid < NCLS) { sInter[tid] = 0.f; sCnt[tid] = 0u; sSumP[tid] = 0.f; }
    if (tid == 0) { sCE = 0.f; sFocal = 0.f; }
    __syncthreads();

    float sumP[NCLS];
#pragma unroll
    for (int c = 0; c < NCLS; ++c) sumP[c] = 0.f;
    float ceAcc = 0.f, foAcc = 0.f;

    int base2 = blockIdx.x * (NTHR * ITERS);    // float2-granular pixel base
    for (int it = 0; it < ITERS; ++it) {
        int i2 = base2 + it * NTHR + tid;
        int pix = i2 * 2;
        int b = pix >> 19;
        int hw = pix & (HW - 1);
        const float* lp = lg + (((size_t)(b * NCLS)) << 19) + hw;
        int2 tt = *reinterpret_cast<const int2*>(masks + pix);
        int t0 = tt.x, t1 = tt.y;

        float S0 = 0.f, S1 = 0.f;
        float lt0 = 0.f, lt1 = 0.f;          // raw target logits (m=0 softmax)
        __half2 ph[NCLS];
#pragma unroll
        for (int c = 0; c < NCLS; ++c) {
            float2 x = *reinterpret_cast<const float2*>(lp + (((size_t)c) << 19));
            bool f0 = (c == t0), f1 = (c == t1);
            // lovasz error (raw logit)
            float e0 = f0 ? (1.f - x.x) : (1.f + x.x);
            float e1 = f1 ? (1.f - x.y) : (1.f + x.y);
            if (e0 > 0.f) {
                int k = (int)(e0 * BSCALE);
                k = (k < NB) ? k : (NB - 1);
                atomicAdd(&hist[c * NB + k], f0 ? 1u : 0x10001u);
            }
            if (e1 > 0.f) {
                int k = (int)(e1 * BSCALE);
                k = (k < NB) ? k : (NB - 1);
                atomicAdd(&hist[c * NB + k], f1 ? 1u : 0x10001u);
            }
            if (f0) lt0 = x.x;
            if (f1) lt1 = x.y;
            float p0 = exp2f(x.x * L2E);
            float p1 = exp2f(x.y * L2E);
            S0 += p0; S1 += p1;
            ph[c] = __floats2half2_rn(p0, p1);
        }

        float inv0 = 1.f / S0, inv1 = 1.f / S1;
#pragma unroll
        for (int c = 0; c < NCLS; ++c) {
            float2 p = __half22float2(ph[c]);
            sumP[c] += p.x * inv0 + p.y * inv1;
        }

        float logpt0 = lt0 - log2f(S0) * LN2;
        float logpt1 = lt1 - log2f(S1) * LN2;
        float pt0 = exp2f(lt0 * L2E) * inv0;
        float pt1 = exp2f(lt1 * L2E) * inv1;
        ceAcc -= logpt0 + logpt1;
        float om0 = 1.f - pt0, om1 = 1.f - pt1;
        foAcc -= 0.25f * (om0 * om0 * logpt0 + om1 * om1 * logpt1);
        atomicAdd(&sInter[t0], pt0);
        atomicAdd(&sInter[t1], pt1);
        atomicAdd(&sCnt[t0], 1u);
        atomicAdd(&sCnt[t1], 1u);
    }

    // wave-level reduction before LDS accumulation
    int lane = tid & 63;
#pragma unroll
    for (int c = 0; c < NCLS; ++c) {
        float v = sumP[c];
#pragma unroll
        for (int s = 32; s > 0; s >>= 1) v += __shfl_xor(v, s);
        if (lane == 0) atomicAdd(&sSumP[c], v);
    }
    {
        float v = ceAcc, w = foAcc;
#pragma unroll
        for (int s = 32; s > 0; s >>= 1) { v += __shfl_xor(v, s); w += __shfl_xor(w, s); }
        if (lane == 0) { atomicAdd(&sCE, v); atomicAdd(&sFocal, w); }
    }
    __syncthreads();

    // flush histogram to one of NREP replicas (halve same-address contention)
    unsigned* gh = gHist + (blockIdx.x & (NREP - 1)) * HIST_ENTRIES;
    for (int k = tid; k < HIST_ENTRIES; k += NTHR) {
        unsigned v = hist[k];
        if (v) atomicAdd(&gh[k], v);
    }
    if (tid < NCLS) {
        atomicAdd(&acc[2 + tid], (double)sInter[tid]);
        atomicAdd(&acc[21 + tid], (double)sSumP[tid]);
        atomicAdd(&acc[40 + tid], (double)sCnt[tid]);
    }
    if (tid == 0) {
        atomicAdd(&acc[0], (double)sCE);
        atomicAdd(&acc[1], (double)sFocal);
    }
}

// ------- K2: per-class suffix scan (one wave per class) + final combine -------
__global__ __launch_bounds__(320) void k_scan_combine(const unsigned* __restrict__ gHist,
                                                      const double* __restrict__ acc,
                                                      float* __restrict__ outv) {
    int tid = threadIdx.x;
    int lane = tid & 63;
    int wave = tid >> 6;
    __shared__ double wsum[5];
    double lov = 0.0;

    for (int r = 0; r < 4; ++r) {
        int c = r * 5 + wave;
        if (c < NCLS) {
            unsigned a[4], bgc[4];
            unsigned cn = 0, cb = 0;
#pragma unroll
            for (int j = 0; j < 4; ++j) {
                int k = c * NB + lane * 4 + j;
                unsigned v0 = gHist[k];
                unsigned v1 = gHist[HIST_ENTRIES + k];
                a[j] = (v0 & 0xFFFFu) + (v1 & 0xFFFFu);
                bgc[j] = (v0 >> 16) + (v1 >> 16);
                cn += a[j];
                cb += bgc[j];
            }
            // inclusive suffix scan over lanes (bucket-descending order)
            unsigned ninc = cn, binc = cb;
#pragma unroll
            for (int s = 1; s < 64; s <<= 1) {
                unsigned tn = __shfl_down(ninc, s, 64);
                unsigned tb = __shfl_down(binc, s, 64);
                if (lane + s < 64) { ninc += tn; binc += tb; }
            }
            double n = (double)(ninc - cn);   // counts strictly above this chunk
            double B = (double)(binc - cb);
            double P = acc[40 + c];
            if (P > 0.5) {
#pragma unroll
                for (int j = 3; j >= 0; --j) {
                    if (a[j]) {
                        double ad = (double)a[j], bd = (double)bgc[j];
                        double Gend = (n + ad) / (P + B + bd);
                        double Gstart = n / (P + B);
                        double emid = ((double)(lane * 4 + j) + 0.5) / 32.0;
                        lov += emid * (Gend - Gstart);
                        n += ad;
                        B += bd;
                    }
                }
            }
        }
    }
#pragma unroll
    for (int s = 32; s > 0; s >>= 1) lov += __shfl_xor(lov, s);
    if (lane == 0) wsum[wave] = lov;
    __syncthreads();

    if (tid == 0) {
        double L = 0.0;
        for (int w = 0; w < 5; ++w) L += wsum[w];
        double ce = acc[0] / (double)NPIX;
        double fo = acc[1] / (double)NPIX;
        double dsum = 0.0, npres = 0.0;
        for (int c = 0; c < NCLS; ++c) {
            double cnt = acc[40 + c];
            if (cnt > 0.5) {
                double inter = acc[2 + c];
                double uni = acc[21 + c] + cnt;
                dsum += (2.0 * inter + 1e-8) / (uni + 1e-8);
                npres += 1.0;
            }
        }
        double dice = (npres > 0.0) ? (1.0 - dsum / npres) : 1.0;
        outv[0] = (float)(ce + fo + dice + 0.5 * (L / (double)NCLS));
    }
}

extern "C" void kernel_launch(void* const* d_in, const int* in_sizes, int n_in,
                              void* d_out, int out_size, void* d_ws, size_t ws_size,
                              hipStream_t stream) {
    const float* lg = (const float*)d_in[0];
    const int* masks = (const int*)d_in[1];
    float* outv = (float*)d_out;

    char* ws = (char*)d_ws;
    double* acc = (double*)ws;                       // 512 B
    unsigned* gHist = (unsigned*)(ws + ACC_BYTES);   // NREP * 19*256*4

    hipMemsetAsync(d_ws, 0, ACC_BYTES + (size_t)NREP * HIST_ENTRIES * 4, stream);

    k_main<<<NBLK, NTHR, 0, stream>>>(lg, masks, gHist, acc);
    k_scan_combine<<<1, 320, 0, stream>>>(gHist, acc, outv);
}